// Round 4
// baseline (304.758 us; speedup 1.0000x reference)
//
#include <hip/hip_runtime.h>
#include <cstdint>
#include <cstddef>

#define IN_F 8192
#define OUT_F 8192
#define BATCH 512
#define KSPLIT 2
#define KSLICE (IN_F / KSPLIT) /* 4096 */
#define BK 64
#define TILES (KSLICE / BK) /* 64 */
#define BM 128
#define BN 256

typedef __bf16 bf16x8 __attribute__((ext_vector_type(8)));
typedef float floatx4 __attribute__((ext_vector_type(4)));

// fp32 -> bf16 round-to-nearest-even
__device__ __forceinline__ ushort f2bf(float f) {
  uint32_t u = __float_as_uint(f);
  u += 0x7FFFu + ((u >> 16) & 1u);
  return (ushort)(u >> 16);
}

// packed int (2 nibbles in low byte) -> bf16x2 of biased weights (q+136):
// low half = 0x4300|hi_nib (even k), high half = 0x4300|lo_nib (odd k)
__device__ __forceinline__ uint32_t dq(int p) {
  uint32_t u = (uint32_t)p;
  return (((u >> 4) & 0xFu) | ((u & 0xFu) << 16)) | 0x43004300u;
}

// async global->LDS, 16B/lane, LDS dest = wave-uniform base + lane*16
__device__ __forceinline__ void gl16(const void* g, uint32_t* l) {
  __builtin_amdgcn_global_load_lds(
      (const __attribute__((address_space(1))) uint32_t*)g,
      (__attribute__((address_space(3))) uint32_t*)l, 16, 0, 0);
}

// Pass 1: x fp32 -> bf16, per-slice rowsums (KSPLIT=2). Zeroes out only on
// the atomic-fallback path (zout != nullptr).
__global__ __launch_bounds__(256) void cvt_rowsum(const float* __restrict__ x,
                                                  ushort* __restrict__ xb,
                                                  float* __restrict__ rowsum,
                                                  float* __restrict__ zout) {
  const int b = blockIdx.x;
  const int t = threadIdx.x;
  const float4* xr = (const float4*)(x + (size_t)b * IN_F);
  ushort4* xo = (ushort4*)(xb + (size_t)b * IN_F);
  float s[2] = {0.f, 0.f};
#pragma unroll
  for (int i = 0; i < 8; ++i) {
    float4 v = xr[i * 256 + t];
    ushort4 o;
    o.x = f2bf(v.x); o.y = f2bf(v.y); o.z = f2bf(v.z); o.w = f2bf(v.w);
    xo[i * 256 + t] = o;
    if (zout) {
      float4 z = {0.f, 0.f, 0.f, 0.f};
      ((float4*)(zout + (size_t)b * OUT_F))[i * 256 + t] = z;
    }
    s[i >> 2] += __uint_as_float((uint32_t)o.x << 16) + __uint_as_float((uint32_t)o.y << 16)
               + __uint_as_float((uint32_t)o.z << 16) + __uint_as_float((uint32_t)o.w << 16);
  }
  __shared__ float red[4][2];
  const int lane = t & 63, wid = t >> 6;
#pragma unroll
  for (int j = 0; j < 2; ++j) {
    float v = s[j];
#pragma unroll
    for (int off = 32; off >= 1; off >>= 1) v += __shfl_down(v, off, 64);
    if (lane == 0) red[wid][j] = v;
  }
  __syncthreads();
  if (t < 2) rowsum[t * BATCH + b] = red[0][t] + red[1][t] + red[2][t] + red[3][t];
}

// Split-K(2) quantized GEMM, 128(m) x 256(n) x (BK=64) tiles, 512 thr,
// 8 waves (2m x 4n), per-wave 64x64 (acc[4][4]). Counted-vmcnt pipeline:
// tile t+1's 4 B-packed loads + 2 A gloads stay in flight across both raw
// s_barriers (vmcnt(6) retires only tile t's 2 A-gloads). XOR swizzle
// slot = chunk ^ (row&7) on A-gload source / B ds_write / fragment reads.
// EPILOGUE: plain stores (ks0->out, ks1->part) + separate reduce kernel.
// Atomic fallback (part==nullptr) if workspace is too small.
__global__ __launch_bounds__(512, 2) void qgemm(const ushort* __restrict__ xb,
                                                const int* __restrict__ pw,
                                                const float* __restrict__ scale,
                                                const float* __restrict__ rowsum,
                                                float* __restrict__ out,
                                                float* __restrict__ part) {
  __shared__ uint32_t As[2 * BM * 32];  // 32 KB
  __shared__ uint32_t Bs[2 * BN * 32];  // 64 KB

  const int tid = threadIdx.x;
  const int lane = tid & 63;
  const int w = tid >> 6;
  const int wm = w >> 2, wn = w & 3;
  const int lr = lane & 15, lq = lane >> 4;

  const int n0 = blockIdx.x * BN;
  const int m0 = blockIdx.y * BM;
  const int ks = blockIdx.z;

  // A gload: wave w instr j covers rows w*16+j*8+(l>>3), slot l&7 linear.
  // Slot p of row r holds chunk p ^ (r&7); r&7 == (l>>3)&7 -> fold into src.
  const char* aSrc = (const char*)xb
      + (size_t)(m0 + w * 16 + (lane >> 3)) * (IN_F * 2)
      + (size_t)ks * (KSLICE * 2)
      + (size_t)((((lane & 7) ^ ((lane >> 3) & 7)) * 16));
  uint32_t* aDst = As + (w * 16) * 32;  // + j*256 + buf*4096

  // B packed: thread t owns row rt = t>>1, chunks {c0,c0+1,c0+4,c0+5}
  const int rt = tid >> 1;
  const int c0 = (tid & 1) * 2;
  const int rk = rt & 7;
  const int* bSrc = pw + (size_t)(n0 + rt) * (IN_F / 2) + ks * (KSLICE / 2);

  // fragment read word-offsets (slot = (kh*4+lq) ^ (lr&7); kh applied as ^16)
  const int key = lr & 7;
  const int aOff = (wm * 64 + lr) * 32 + ((lq ^ key) * 4);
  const int bOff = (wn * 64 + lr) * 32 + ((lq ^ key) * 4);

  floatx4 acc[4][4] = {};

  auto stB = [&](int nb, int q, int4 p) {
    int4 u;
    u.x = dq(p.x); u.y = dq(p.y); u.z = dq(p.z); u.w = dq(p.w);
    *(int4*)(Bs + nb * 8192 + rt * 32 + ((q ^ rk) * 4)) = u;
  };

#define RD_BV(kh)                                                            \
  _Pragma("unroll") for (int fn = 0; fn < 4; ++fn)                           \
      bv[fn] = *(const bf16x8*)(Bs + (((bOff + fn * 512) ^ ((kh)*16)) + buf * 8192));
#define RD_AV(kh)                                                            \
  _Pragma("unroll") for (int fm = 0; fm < 4; ++fm)                           \
      av[fm] = *(const bf16x8*)(As + (((aOff + fm * 512) ^ ((kh)*16)) + buf * 4096));
#define MFMA_BLK()                                                           \
  __builtin_amdgcn_s_setprio(1);                                             \
  _Pragma("unroll") for (int fm = 0; fm < 4; ++fm)                           \
      _Pragma("unroll") for (int fn = 0; fn < 4; ++fn)                       \
          acc[fm][fn] = __builtin_amdgcn_mfma_f32_16x16x32_bf16(             \
              av[fm], bv[fn], acc[fm][fn], 0, 0, 0);                         \
  __builtin_amdgcn_s_setprio(0);

  // ---- prologue: stage tile 0 into buf 0 ----
  {
    int4 p0 = *(const int4*)(bSrc + c0 * 4);
    int4 p1 = *(const int4*)(bSrc + c0 * 4 + 4);
    int4 p2 = *(const int4*)(bSrc + (c0 + 4) * 4);
    int4 p3 = *(const int4*)(bSrc + (c0 + 4) * 4 + 4);
    stB(0, c0, p0); stB(0, c0 + 1, p1); stB(0, c0 + 4, p2); stB(0, c0 + 5, p3);
    gl16(aSrc, aDst);
    gl16(aSrc + 131072, aDst + 256);
    asm volatile("s_waitcnt lgkmcnt(0)" ::: "memory");
  }

  for (int t = 0; t < TILES - 1; ++t) {
    const int buf = t & 1, nb = buf ^ 1;
    // issue staging for tile t+1
    const int* bs = bSrc + (t + 1) * 32;
    int4 pb0 = *(const int4*)(bs + c0 * 4);
    int4 pb1 = *(const int4*)(bs + c0 * 4 + 4);
    int4 pb2 = *(const int4*)(bs + (c0 + 4) * 4);
    int4 pb3 = *(const int4*)(bs + (c0 + 4) * 4 + 4);
    const char* as = aSrc + (size_t)(t + 1) * 128;
    gl16(as, aDst + nb * 4096);
    gl16(as + 131072, aDst + nb * 4096 + 256);
    // retire ONLY tile t's 2 A-gloads; t+1's 6 ops stay in flight
    asm volatile("s_waitcnt vmcnt(6)" ::: "memory");
    asm volatile("s_barrier" ::: "memory");  // publish tile t staging

    bf16x8 av[4], bv[4];
    RD_BV(0); RD_AV(0);
    MFMA_BLK();
    RD_BV(1); RD_AV(1);
    MFMA_BLK();
    // B(t+1) unpack+write last: pb loads got barrier + 16 ds_reads + 32 MFMA
    // of cover before first use
    stB(nb, c0, pb0); stB(nb, c0 + 1, pb1);
    stB(nb, c0 + 4, pb2); stB(nb, c0 + 5, pb3);

    asm volatile("s_waitcnt lgkmcnt(0)" ::: "memory");  // drain own B writes
    asm volatile("s_barrier" ::: "memory");             // tile boundary
  }

  // ---- tail tile (no staging) ----
  {
    const int buf = (TILES - 1) & 1;
    asm volatile("s_waitcnt vmcnt(0)" ::: "memory");
    asm volatile("s_barrier" ::: "memory");
    bf16x8 av[4], bv[4];
    RD_BV(0); RD_AV(0);
    MFMA_BLK();
    RD_BV(1); RD_AV(1);
    MFMA_BLK();
  }

  // epilogue: C/D layout col=lane&15, row=(lane>>4)*4+reg
  const int omb = m0 + wm * 64 + lq * 4;
  const int on = n0 + wn * 64 + lr;
  float scv[4];
#pragma unroll
  for (int fn = 0; fn < 4; ++fn) scv[fn] = scale[on + fn * 16];
  float rsv[4][4];
#pragma unroll
  for (int mi = 0; mi < 4; ++mi)
#pragma unroll
    for (int rr = 0; rr < 4; ++rr)
      rsv[mi][rr] = rowsum[ks * BATCH + omb + mi * 16 + rr];

  if (part) {
    float* dst = ks ? part : out;
#pragma unroll
    for (int mi = 0; mi < 4; ++mi)
#pragma unroll
      for (int fn = 0; fn < 4; ++fn) {
        const float s = scv[fn];
        float* op = dst + (size_t)(omb + mi * 16) * OUT_F + (on + fn * 16);
#pragma unroll
        for (int rr = 0; rr < 4; ++rr)
          op[(size_t)rr * OUT_F] = s * (acc[mi][fn][rr] - 136.f * rsv[mi][rr]);
      }
  } else {
#pragma unroll
    for (int mi = 0; mi < 4; ++mi)
#pragma unroll
      for (int fn = 0; fn < 4; ++fn) {
        const float s = scv[fn];
        float* op = out + (size_t)(omb + mi * 16) * OUT_F + (on + fn * 16);
#pragma unroll
        for (int rr = 0; rr < 4; ++rr)
          atomicAdd(op + (size_t)rr * OUT_F, s * (acc[mi][fn][rr] - 136.f * rsv[mi][rr]));
      }
  }
#undef RD_BV
#undef RD_AV
#undef MFMA_BLK
}

// out += part, grid-strided float4
__global__ __launch_bounds__(256) void reduce_add(float* __restrict__ out,
                                                  const float* __restrict__ part) {
  const size_t n = (size_t)BATCH * OUT_F / 4;
  float4* o4 = (float4*)out;
  const float4* p4 = (const float4*)part;
  for (size_t i = (size_t)blockIdx.x * 256 + threadIdx.x; i < n;
       i += (size_t)gridDim.x * 256) {
    float4 a = o4[i];
    float4 b = p4[i];
    a.x += b.x; a.y += b.y; a.z += b.z; a.w += b.w;
    o4[i] = a;
  }
}

extern "C" void kernel_launch(void* const* d_in, const int* in_sizes, int n_in,
                              void* d_out, int out_size, void* d_ws, size_t ws_size,
                              hipStream_t stream) {
  const float* x = (const float*)d_in[0];
  const int* pw = (const int*)d_in[1];
  const float* scale = (const float*)d_in[2];
  float* out = (float*)d_out;

  ushort* xb = (ushort*)d_ws;  // 8 MiB
  float* rowsum = (float*)((char*)d_ws + (size_t)8 * 1024 * 1024);  // 2x512 f32
  const size_t need = (size_t)8 * 1024 * 1024 + 65536 + (size_t)BATCH * OUT_F * 4;
  float* part = (ws_size >= need)
      ? (float*)((char*)d_ws + (size_t)8 * 1024 * 1024 + 65536)
      : nullptr;

  cvt_rowsum<<<BATCH, 256, 0, stream>>>(x, xb, rowsum, part ? nullptr : out);
  dim3 grid(OUT_F / BN, BATCH / BM, KSPLIT);
  qgemm<<<grid, 512, 0, stream>>>(xb, pw, scale, rowsum, out, part);
  if (part) reduce_add<<<2048, 256, 0, stream>>>(out, part);
}